// Round 14
// baseline (176.942 us; speedup 1.0000x reference)
//
#include <hip/hip_runtime.h>

// ---------------- types / helpers ----------------
typedef __attribute__((ext_vector_type(8))) short bf16x8;      // 8 bf16 (4 VGPRs)
typedef __attribute__((ext_vector_type(8))) _Float16 f16x8;    // 8 fp16 (4 VGPRs)
typedef __attribute__((ext_vector_type(4))) float f32x4;       // 16x16 MFMA C/D frag
typedef __attribute__((ext_vector_type(16))) float f32x16;     // 32x32 MFMA C/D frag
typedef __attribute__((ext_vector_type(8))) unsigned short u16x8;

#define MFMA16(a, b, c)  __builtin_amdgcn_mfma_f32_16x16x32_bf16((a), (b), (c), 0, 0, 0)
#define MFMA16F(a, b, c) __builtin_amdgcn_mfma_f32_16x16x32_f16((a), (b), (c), 0, 0, 0)
#define MFMA32(a, b, c)  __builtin_amdgcn_mfma_f32_32x32x16_bf16((a), (b), (c), 0, 0, 0)
#define MFMA32F(a, b, c) __builtin_amdgcn_mfma_f32_32x32x16_f16((a), (b), (c), 0, 0, 0)

__device__ __forceinline__ unsigned short f2bf(float v) {
    unsigned u = __float_as_uint(v);
    return (unsigned short)((u + 0x7fffu + ((u >> 16) & 1u)) >> 16);  // RN
}
__device__ __forceinline__ float bf2f(unsigned short h) {
    return __uint_as_float(((unsigned)h) << 16);
}
__device__ __forceinline__ unsigned short f2h(float v) {
    union { _Float16 h; unsigned short u; } cv; cv.h = (_Float16)v; return cv.u;
}
// async global->LDS DMA, 16B/lane; LDS dest = base + lane*16 (hardware), global src per-lane.
__device__ __forceinline__ void gll16(const void* g, void* l) {
    __builtin_amdgcn_global_load_lds(
        (const __attribute__((address_space(1))) unsigned int*)g,
        (__attribute__((address_space(3))) unsigned int*)l, 16, 0, 0);
}
// pack two f32 -> one u32 of 2 bf16 (lo = src0, hi = src1)
__device__ __forceinline__ unsigned cvtpk(float lo, float hi) {
    unsigned r;
    asm("v_cvt_pk_bf16_f32 %0, %1, %2" : "=v"(r) : "v"(lo), "v"(hi));
    return r;
}
// swap lanes[32:63] of a with lanes[0:31] of b (in place).
// ONLY safe when a and b hold provably distinct values (round-8 lesson: equal-valued
// "+v" operands can be register-coalesced into v_permlane32_swap v0,v0 -> wrong result).
#define PSWAP(a, b) asm volatile("v_permlane32_swap_b32 %0, %1" : "+v"(a), "+v"(b))

__device__ __forceinline__ f32x16 zero16() {
    f32x16 z;
#pragma unroll
    for (int j = 0; j < 16; j++) z[j] = 0.f;
    return z;
}

// B=8, C=256, H=W=64, N=4096, HID=128
#define NB 8
#define NC 256
#define NN 4096
#define HID 128
#define ELEMS (NB * NN * HID)            // 4,194,304 per [B,N,128] 16-bit buffer

// ---------------- kernel 1: projections v3 (round-12 config) ----------------
// theta/phi: fp16 single-term MFMA. g: bf16 1-term.
// Outputs: theta -> Qf fp16 (pre-scaled by sqrt(128)*log2e), phi -> Kf fp16, g -> Vt bf16.
__global__ __launch_bounds__(256, 2)
void proj_kernel(const float* __restrict__ x,
                 const float* __restrict__ w_theta,
                 const float* __restrict__ w_phi,
                 const float* __restrict__ w_g,
                 unsigned short* __restrict__ Qf, unsigned short* __restrict__ Kf,
                 unsigned short* __restrict__ Vt) {
    __shared__ __align__(16) unsigned char LdsRaw[128 * 65 * 4];  // 33,280 B (union)
    float (*xs)[129] = reinterpret_cast<float(*)[129]>(LdsRaw);
    unsigned int (*Tb)[65] = reinterpret_cast<unsigned int(*)[65]>(LdsRaw);

    const int t = threadIdx.x;
    const int w = t >> 6, lane = t & 63;
    const int g = lane >> 4, c = lane & 15;
    const int n0 = blockIdx.x * 128;
    const int which = blockIdx.y;
    const int b = blockIdx.z;
    const float* wsel = (which == 0) ? w_theta : ((which == 1) ? w_phi : w_g);

    f32x4 acc[2][8];
#pragma unroll
    for (int mi = 0; mi < 2; mi++)
#pragma unroll
        for (int nt = 0; nt < 8; nt++) acc[mi][nt] = (f32x4){0.f, 0.f, 0.f, 0.f};

    const int srow = w * 16 + (lane >> 2);
    const int snq = (lane & 3) * 32;

    for (int k0 = 0; k0 < NC; k0 += 64) {
        __syncthreads();
        {
            const float* src = x + ((size_t)(b * NC + k0 + srow)) * NN + n0 + snq;
            float4 v[8];
#pragma unroll
            for (int u = 0; u < 8; u++) v[u] = *(const float4*)(src + 4 * u);
#pragma unroll
            for (int u = 0; u < 8; u++) {
                xs[srow][snq + 4 * u + 0] = v[u].x;
                xs[srow][snq + 4 * u + 1] = v[u].y;
                xs[srow][snq + 4 * u + 2] = v[u].z;
                xs[srow][snq + 4 * u + 3] = v[u].w;
            }
        }
        __syncthreads();

        if (which < 2) {
#pragma unroll
            for (int s = 0; s < 2; s++) {
                f16x8 wf2[2];
#pragma unroll
                for (int mi = 0; mi < 2; mi++) {
                    const float* wp = wsel + (size_t)(w * 32 + mi * 16 + c) * NC + k0 + s * 32 + g * 8;
                    float av[8];
                    *(float4*)&av[0] = *(const float4*)wp;
                    *(float4*)&av[4] = *(const float4*)(wp + 4);
#pragma unroll
                    for (int j = 0; j < 8; j++) wf2[mi][j] = (_Float16)av[j];
                }
#pragma unroll
                for (int nt = 0; nt < 8; nt++) {
                    f16x8 xf;
#pragma unroll
                    for (int j = 0; j < 8; j++) xf[j] = (_Float16)xs[s * 32 + g * 8 + j][nt * 16 + c];
#pragma unroll
                    for (int mi = 0; mi < 2; mi++)
                        acc[mi][nt] = MFMA16F(wf2[mi], xf, acc[mi][nt]);
                }
            }
        } else {
#pragma unroll
            for (int s = 0; s < 2; s++) {
                bf16x8 wh[2];
#pragma unroll
                for (int mi = 0; mi < 2; mi++) {
                    const float* wp = wsel + (size_t)(w * 32 + mi * 16 + c) * NC + k0 + s * 32 + g * 8;
                    float av[8];
                    *(float4*)&av[0] = *(const float4*)wp;
                    *(float4*)&av[4] = *(const float4*)(wp + 4);
#pragma unroll
                    for (int j = 0; j < 8; j++) wh[mi][j] = (short)f2bf(av[j]);
                }
#pragma unroll
                for (int nt = 0; nt < 8; nt++) {
                    bf16x8 xh;
#pragma unroll
                    for (int j = 0; j < 8; j++) xh[j] = (short)f2bf(xs[s * 32 + g * 8 + j][nt * 16 + c]);
#pragma unroll
                    for (int mi = 0; mi < 2; mi++)
                        acc[mi][nt] = MFMA16(wh[mi], xh, acc[mi][nt]);
                }
            }
        }
    }

    if (which == 2) {
#pragma unroll
        for (int mi = 0; mi < 2; mi++)
#pragma unroll
            for (int nt = 0; nt < 8; nt++)
#pragma unroll
                for (int r = 0; r < 4; r++) {
                    int o = w * 32 + mi * 16 + 4 * g + r;
                    Vt[((size_t)(b * HID + o)) * NN + n0 + nt * 16 + c] = f2bf(acc[mi][nt][r]);
                }
    } else {
        unsigned short* dh = (which == 0) ? Qf : Kf;
        const float qscale = (which == 0) ? 16.32223142f : 1.0f;  // sqrt(128)*log2(e) into theta
        for (int h = 0; h < 2; h++) {
            __syncthreads();   // protects xs->Tb union reuse
#pragma unroll
            for (int mi = 0; mi < 2; mi++)
#pragma unroll
                for (int q2 = 0; q2 < 4; q2++) {
                    int nt = h * 4 + q2;
#pragma unroll
                    for (int r = 0; r < 4; r++)
                        Tb[w * 32 + mi * 16 + 4 * g + r][q2 * 16 + c] =
                            (unsigned)f2h(acc[mi][nt][r] * qscale);
                }
            __syncthreads();
            {
                int nl = t & 63;
                int og = (t >> 6) * 32;
                int n = n0 + h * 64 + nl;
                u16x8 vh[4];
#pragma unroll
                for (int k = 0; k < 32; k++)
                    vh[k >> 3][k & 7] = (unsigned short)Tb[og + k][nl];
                size_t base = ((size_t)(b * NN + n)) * HID + og;
#pragma unroll
                for (int q = 0; q < 4; q++)
                    *(u16x8*)(dh + base + q * 8) = vh[q];
            }
        }
    }
}

// ---------------- kernel 2: flash attention v10 — 2-stage software pipeline ----------------
// 4 LDS buffers (64 KB). Prologue computes QK(0); iter tI does:
//   vmcnt(tile tI+1 landed) -> barrier -> STAGE(tI+3) -> [ QK(tI+1)  ||  softmax(tI)+PV(tI) ]
// QK(tI+1) (MFMA+LDS) is independent of softmax(tI) (VALU) -> pipes overlap within a wave.
// Buffers: STAGE (tI+3)%4, PV reads tI%4, QK reads (tI+1)%4 — pairwise distinct; (tI+3)%4's
// last reader was PV(tI-1), sequenced before this iter's barrier. Math identical to v8.
template<int ZBITS>
__global__ __launch_bounds__(256, 2)
void attn_kernel(const unsigned short* __restrict__ Qf, const unsigned short* __restrict__ Kf,
                 const unsigned short* __restrict__ Vt,
                 unsigned short* __restrict__ Yp, float* __restrict__ Ms, float* __restrict__ Ss,
                 int kv_len) {
    __shared__ __align__(16) unsigned char KV_lds[4][16384];   // per buf: K [0,8K) V [8K,16K)

    const int t = threadIdx.x;
    const int w = t >> 6, lane = t & 63;
    const int l31 = lane & 31, hi = lane >> 5;
    const int bid = blockIdx.x;
    const int b = bid & 7;                                  // batch -> XCD pin
    const int z = (bid >> 3) & ((1 << ZBITS) - 1);
    const int qx = bid >> (3 + ZBITS);
    const int q0 = qx * 128 + w * 32;

    const int kvb = z * kv_len;
    const char* KG = (const char*)(Kf + ((size_t)(b * NN) + kvb) * HID);
    const char* VG = (const char*)(Vt + ((size_t)(b * HID)) * NN + kvb);

    // staging lane constants: wave w handles slots {2w, 2w+1} of K and of V
    const int si0 = w * 2, si1 = w * 2 + 1;
    const int krow0 = si0 * 4 + (lane >> 4), krow1 = si1 * 4 + (lane >> 4);  // K rows 0..31
    const int kq = lane & 15;
    const int kqg0 = kq ^ (krow0 & 15), kqg1 = kq ^ (krow1 & 15);            // 16-chunk swizzle
    const int vrow0 = si0 * 16 + (lane >> 2), vrow1 = si1 * 16 + (lane >> 2); // V rows 0..127
    const int vm = lane & 3;
    const int vmg0 = vm ^ ((vrow0 >> 1) & 3), vmg1 = vm ^ ((vrow1 >> 1) & 3);

#define STAGE(buf, kvoff)                                                                        \
    do {                                                                                         \
        gll16(KG + (size_t)((kvoff) + krow0) * 256 + kqg0 * 16, (buf) + si0 * 1024);             \
        gll16(KG + (size_t)((kvoff) + krow1) * 256 + kqg1 * 16, (buf) + si1 * 1024);             \
        gll16(VG + (size_t)vrow0 * 8192 + (size_t)(kvoff) * 2 + vmg0 * 16, (buf) + 8192 + si0 * 1024); \
        gll16(VG + (size_t)vrow1 * 8192 + (size_t)(kvoff) * 2 + vmg1 * 16, (buf) + 8192 + si1 * 1024); \
    } while (0)

    const int krbase = l31 * 256;
    const int kkey = l31 & 15;
    const int vkey = (l31 >> 1) & 3;

#define QKT(dst, kptr)                                                        \
    do {                                                                      \
        (dst) = zero16();                                                     \
        __builtin_amdgcn_s_setprio(1);                                        \
        _Pragma("unroll")                                                     \
        for (int s = 0; s < 8; s++) {                                         \
            const int off = krbase + (((2 * s + hi) ^ kkey) * 16);            \
            f16x8 kf = *(const f16x8*)((kptr) + off);                         \
            (dst) = MFMA32F(kf, qf[s], (dst));                                \
        }                                                                     \
        __builtin_amdgcn_s_setprio(0);                                        \
    } while (0)

    const int ntl = kv_len >> 5;   // KVBLK=32

    // prologue: tiles 0,1 in flight
    STAGE(&KV_lds[0][0], 0);
    if (ntl > 1) STAGE(&KV_lds[1][0], 32);

    // Q fragments (fp16, B-operand, 32 rows): lane reads Q[q0+l31][k = 16s + hi*8 .. +7]
    f16x8 qf[8];
    {
        const unsigned short* qp = Qf + ((size_t)(b * NN) + q0 + l31) * HID + hi * 8;
#pragma unroll
        for (int s = 0; s < 8; s++) qf[s] = *(const f16x8*)(qp + s * 16);
    }

    float mstar = -3.0e38f, sacc = 0.f;   // per-lane, q = l31 (exp2-domain; Q pre-scaled)
    f32x16 yacc[4];
#pragma unroll
    for (int dt = 0; dt < 4; dt++) yacc[dt] = zero16();

    // prologue: wait tile 0, stage tile 2, compute QK(0)
    if (ntl > 1) { asm volatile("s_waitcnt vmcnt(4)" ::: "memory"); }
    else         { asm volatile("s_waitcnt vmcnt(0)" ::: "memory"); }
    __builtin_amdgcn_sched_barrier(0);
    __builtin_amdgcn_s_barrier();
    __builtin_amdgcn_sched_barrier(0);
    if (ntl > 2) STAGE(&KV_lds[2][0], 64);
    f32x16 stv_prev;
    QKT(stv_prev, &KV_lds[0][0]);

    for (int tI = 0; tI < ntl; ++tI) {
        // ensure tile tI+1 landed (it's needed by QK below). Outstanding at entry:
        // tiles tI+1 and (if staged) tI+2 -> vmcnt(4) pins tI+1 when tI+2 exists, else 0.
        if (tI + 2 < ntl) { asm volatile("s_waitcnt vmcnt(4)" ::: "memory"); }
        else              { asm volatile("s_waitcnt vmcnt(0)" ::: "memory"); }
        __builtin_amdgcn_sched_barrier(0);
        __builtin_amdgcn_s_barrier();
        __builtin_amdgcn_sched_barrier(0);

        if (tI + 3 < ntl) STAGE(&KV_lds[(tI + 3) & 3][0], (tI + 3) * 32);

        // ---- QK^T of NEXT tile (MFMA+LDS) — independent of softmax/PV below ----
        f32x16 stv_next;
        const bool have_next = (tI + 1 < ntl);
        if (have_next) QKT(stv_next, &KV_lds[(tI + 1) & 3][0]);

        // ---- softmax of tile tI (VALU; lane-local, one cross-half shfl max) ----
        f32x16 stv = stv_prev;
        float m = stv[0];
#pragma unroll
        for (int r = 1; r < 16; r++) m = fmaxf(m, stv[r]);
        m = fmaxf(m, __shfl_xor(m, 32));

        if (__any(m > mstar + 65.f)) {         // defer-max: rescale only on headroom breach
            float nm = fmaxf(mstar, m);
            float corr = exp2f(mstar - nm);    // first tile: ~0
            mstar = nm;
            sacc *= corr;
            float cr[16];
#pragma unroll
            for (int r = 0; r < 16; r++)
                cr[r] = __shfl(corr, (r & 3) + 8 * (r >> 2) + 4 * hi);  // corr of q-row of reg r
#pragma unroll
            for (int dt = 0; dt < 4; dt++)
#pragma unroll
                for (int r = 0; r < 16; r++) yacc[dt][r] *= cr[r];
        }

        float p[16];
#pragma unroll
        for (int r = 0; r < 16; r++) p[r] = exp2f(stv[r] - mstar);
        float ls = 0.f;
#pragma unroll
        for (int r = 0; r < 16; r++) ls += p[r];
        sacc += ls;

        // ---- P -> PV A-frag: 8 cvt_pk + 4 permlane32_swap (distinct values) ----
        unsigned X0 = cvtpk(p[0], p[1]),   X1 = cvtpk(p[2], p[3]);
        unsigned X2 = cvtpk(p[4], p[5]),   X3 = cvtpk(p[6], p[7]);
        unsigned X4 = cvtpk(p[8], p[9]),   X5 = cvtpk(p[10], p[11]);
        unsigned X6 = cvtpk(p[12], p[13]), X7 = cvtpk(p[14], p[15]);
        PSWAP(X0, X2); PSWAP(X1, X3);      // k 0..15 frag
        PSWAP(X4, X6); PSWAP(X5, X7);      // k 16..31 frag
        union { unsigned u[4]; bf16x8 v; } pa, pb;
        pa.u[0] = X0; pa.u[1] = X1; pa.u[2] = X2; pa.u[3] = X3;
        pb.u[0] = X4; pb.u[1] = X5; pb.u[2] = X6; pb.u[3] = X7;
        bf16x8 pf0 = pa.v, pf1 = pb.v;

        // ---- PV: Y += P * V (bf16), from buf[tI & 3] ----
        const unsigned char* V_l = &KV_lds[tI & 3][8192];
        __builtin_amdgcn_s_setprio(1);
#pragma unroll
        for (int dt = 0; dt < 4; dt++) {
            const int vbase = (dt * 32 + l31) * 64;
            bf16x8 v0 = *(const bf16x8*)(V_l + vbase + ((hi ^ vkey) * 16));
            bf16x8 v1 = *(const bf16x8*)(V_l + vbase + (((2 + hi) ^ vkey) * 16));
            yacc[dt] = MFMA32(pf0, v0, yacc[dt]);
            yacc[dt] = MFMA32(pf1, v1, yacc[dt]);
        }
        __builtin_amdgcn_s_setprio(0);

        if (have_next) stv_prev = stv_next;
        // no trailing barrier: next overwrite target (tI+4)%4 is staged only after the
        // NEXT iteration's barrier, by which time this iteration's reads are done.
    }

    float stot = sacc + __shfl_xor(sacc, 32);  // total row-sum for q=l31

    if (ZBITS == 0) {
        float inv = 1.0f / stot;
        float ivr[16];
#pragma unroll
        for (int r = 0; r < 16; r++)
            ivr[r] = __shfl(inv, (r & 3) + 8 * (r >> 2) + 4 * hi);
        const size_t obase = (size_t)(b * NN) + q0;
#pragma unroll
        for (int dt = 0; dt < 4; dt++)
#pragma unroll
            for (int r = 0; r < 16; r++) {
                int q = (r & 3) + 8 * (r >> 2) + 4 * hi;
                Yp[(obase + q) * HID + dt * 32 + l31] = f2bf(yacc[dt][r] * ivr[r]);
            }
    } else {
        const size_t base = (((size_t)z * NB + b) * NN + q0);
#pragma unroll
        for (int dt = 0; dt < 4; dt++)
#pragma unroll
            for (int r = 0; r < 16; r++) {
                int q = (r & 3) + 8 * (r >> 2) + 4 * hi;
                Yp[(base + q) * HID + dt * 32 + l31] = f2bf(yacc[dt][r]);
            }
        if (hi == 0) {
            Ms[base + l31] = mstar;
            Ss[base + l31] = stot;
        }
    }
#undef QKT
#undef STAGE
}

// ---------------- kernel 3: output projection — bf16 MFMA + residual (unchanged) ----------------
template<int NS>
__global__ __launch_bounds__(256, 2)
void out_kernel(const float* __restrict__ x, const float* __restrict__ w_out,
                const unsigned short* __restrict__ Yp,
                const float* __restrict__ Ms, const float* __restrict__ Ss,
                float* __restrict__ out) {
    __shared__ __align__(16) unsigned short Yl[128][136];  // 34,816 B

    const int t = threadIdx.x;
    const int w = t >> 6, lane = t & 63;
    const int g = lane >> 4, c = lane & 15;
    const int n0 = blockIdx.x * 128;
    const int b = blockIdx.y;

    {   // stage (+combine) Y tile
        int nl = t >> 1, oh = (t & 1) * 64;
        size_t qi = (size_t)b * NN + n0 + nl;
        if (NS == 0) {
            const unsigned short* src = Yp + qi * HID + oh;
#pragma unroll
            for (int i = 0; i < 8; i++)
                *(u16x8*)&Yl[nl][oh + i * 8] = *(const u16x8*)(src + i * 8);
        } else {
            const size_t NBNN = (size_t)NB * NN;
            float Mv[NS > 0 ? NS : 1], Wt[NS > 0 ? NS : 1];
            float M = -3.0e38f;
#pragma unroll
            for (int zz = 0; zz < NS; zz++) { Mv[zz] = Ms[zz * NBNN + qi]; M = fmaxf(M, Mv[zz]); }
            float S = 0.f;
#pragma unroll
            for (int zz = 0; zz < NS; zz++) { Wt[zz] = exp2f(Mv[zz] - M); S += Ss[zz * NBNN + qi] * Wt[zz]; }
            float invS = 1.f / S;
#pragma unroll
            for (int zz = 0; zz < NS; zz++) Wt[zz] *= invS;
#pragma unroll
            for (int i = 0; i < 8; i++) {
                float f[8] = {0.f, 0.f, 0.f, 0.f, 0.f, 0.f, 0.f, 0.f};
#pragma unroll
                for (int zz = 0; zz < NS; zz++) {
                    u16x8 a = *(const u16x8*)(Yp + (zz * NBNN + qi) * HID + oh + i * 8);
#pragma unroll
                    for (int j = 0; j < 8; j++) f[j] = fmaf(bf2f(a[j]), Wt[zz], f[j]);
                }
                u16x8 vv;
#pragma unroll
                for (int j = 0; j < 8; j++) vv[j] = f2bf(f[j]);
                *(u16x8*)&Yl[nl][oh + i * 8] = vv;
            }
        }
    }
    __syncthreads();

    f32x4 acc[4][8];
#pragma unroll
    for (int mi = 0; mi < 4; mi++)
#pragma unroll
        for (int nt = 0; nt < 8; nt++) acc[mi][nt] = (f32x4){0.f, 0.f, 0.f, 0.f};

#pragma unroll
    for (int s = 0; s < 4; s++) {
        bf16x8 wf[4];
#pragma unroll
        for (int mi = 0; mi < 4; mi++) {
            const float* wp = w_out + (size_t)(w * 64 + mi * 16 + c) * HID + s * 32 + g * 8;
            float av[8];
            *(float4*)&av[0] = *(const float4*)wp;
            *(float4*)&av[4] = *(const float4*)(wp + 4);
#pragma unroll
            for (int j = 0; j < 8; j++) wf[mi][j] = (short)f2bf(av[j]);
        }
#pragma unroll
        for (int nt = 0; nt < 8; nt++) {
            bf16x8 yf = *(const bf16x8*)&Yl[nt * 16 + c][s * 32 + g * 8];
#pragma unroll
            for (int mi = 0; mi < 4; mi++) acc[mi][nt] = MFMA16(wf[mi], yf, acc[mi][nt]);
        }
    }

#pragma unroll
    for (int mi = 0; mi < 4; mi++)
#pragma unroll
        for (int nt = 0; nt < 8; nt++)
#pragma unroll
            for (int r = 0; r < 4; r++) {
                int cg = w * 64 + mi * 16 + 4 * g + r;
                size_t idx = ((size_t)(b * NC + cg)) * NN + n0 + nt * 16 + c;
                out[idx] = x[idx] + acc[mi][nt][r];
            }
}

// ---------------- launch ----------------
extern "C" void kernel_launch(void* const* d_in, const int* in_sizes, int n_in,
                              void* d_out, int out_size, void* d_ws, size_t ws_size,
                              hipStream_t stream) {
    const float* x = (const float*)d_in[0];
    const float* w_phi = (const float*)d_in[1];
    const float* w_theta = (const float*)d_in[2];
    const float* w_g = (const float*)d_in[3];
    const float* w_out = (const float*)d_in[4];
    float* out = (float*)d_out;

    const size_t BUF = (size_t)ELEMS * 2;      // 8,388,608 B per 16-bit buffer
    const size_t MSB = (size_t)NB * NN * 4;    // 131,072 B per [B,N] f32 array
    if (ws_size < 4 * BUF) return;

    unsigned short* Qf = (unsigned short*)d_ws;
    unsigned short* Kf = (unsigned short*)((char*)d_ws + 1 * BUF);
    unsigned short* Vt = (unsigned short*)((char*)d_ws + 2 * BUF);

    proj_kernel<<<dim3(32, 3, 8), 256, 0, stream>>>(x, w_theta, w_phi, w_g, Qf, Kf, Vt);

    if (ws_size >= 7 * BUF + 8 * MSB) {
        // split-kv x4: 1024 blocks x 256 thr (8b x 4z x 32qx)
        unsigned short* Yp = (unsigned short*)((char*)d_ws + 3 * BUF);
        float* Ms = (float*)((char*)d_ws + 7 * BUF);
        float* Ss = (float*)((char*)d_ws + 7 * BUF + 4 * MSB);
        attn_kernel<2><<<dim3(1024), 256, 0, stream>>>(Qf, Kf, Vt, Yp, Ms, Ss, NN / 4);
        out_kernel<4><<<dim3(32, NB), 256, 0, stream>>>(x, w_out, Yp, Ms, Ss, out);
    } else if (ws_size >= 5 * BUF + 4 * MSB) {
        // split-kv x2 fallback: 512 blocks x 256 thr
        unsigned short* Yp = (unsigned short*)((char*)d_ws + 3 * BUF);
        float* Ms = (float*)((char*)d_ws + 5 * BUF);
        float* Ss = (float*)((char*)d_ws + 5 * BUF + 2 * MSB);
        attn_kernel<1><<<dim3(512), 256, 0, stream>>>(Qf, Kf, Vt, Yp, Ms, Ss, NN / 2);
        out_kernel<2><<<dim3(32, NB), 256, 0, stream>>>(x, w_out, Yp, Ms, Ss, out);
    } else {
        unsigned short* Yb = (unsigned short*)((char*)d_ws + 3 * BUF);
        attn_kernel<0><<<dim3(256), 256, 0, stream>>>(Qf, Kf, Vt, Yb, nullptr, nullptr, NN);
        out_kernel<0><<<dim3(32, NB), 256, 0, stream>>>(x, w_out, Yb, nullptr, nullptr, out);
    }
}

// Round 15
// 168.273 us; speedup vs baseline: 1.0515x; 1.0515x over previous
//
#include <hip/hip_runtime.h>

// ---------------- types / helpers ----------------
typedef __attribute__((ext_vector_type(8))) short bf16x8;      // 8 bf16 (4 VGPRs)
typedef __attribute__((ext_vector_type(8))) _Float16 f16x8;    // 8 fp16 (4 VGPRs)
typedef __attribute__((ext_vector_type(4))) float f32x4;       // 16x16 MFMA C/D frag
typedef __attribute__((ext_vector_type(16))) float f32x16;     // 32x32 MFMA C/D frag
typedef __attribute__((ext_vector_type(8))) unsigned short u16x8;

#define MFMA16(a, b, c)  __builtin_amdgcn_mfma_f32_16x16x32_bf16((a), (b), (c), 0, 0, 0)
#define MFMA16F(a, b, c) __builtin_amdgcn_mfma_f32_16x16x32_f16((a), (b), (c), 0, 0, 0)
#define MFMA32(a, b, c)  __builtin_amdgcn_mfma_f32_32x32x16_bf16((a), (b), (c), 0, 0, 0)
#define MFMA32F(a, b, c) __builtin_amdgcn_mfma_f32_32x32x16_f16((a), (b), (c), 0, 0, 0)

__device__ __forceinline__ unsigned short f2bf(float v) {
    unsigned u = __float_as_uint(v);
    return (unsigned short)((u + 0x7fffu + ((u >> 16) & 1u)) >> 16);  // RN
}
__device__ __forceinline__ float bf2f(unsigned short h) {
    return __uint_as_float(((unsigned)h) << 16);
}
__device__ __forceinline__ unsigned short f2h(float v) {
    union { _Float16 h; unsigned short u; } cv; cv.h = (_Float16)v; return cv.u;
}
// async global->LDS DMA, 16B/lane; LDS dest = base + lane*16 (hardware), global src per-lane.
__device__ __forceinline__ void gll16(const void* g, void* l) {
    __builtin_amdgcn_global_load_lds(
        (const __attribute__((address_space(1))) unsigned int*)g,
        (__attribute__((address_space(3))) unsigned int*)l, 16, 0, 0);
}
// pack two f32 -> one u32 of 2 bf16 (lo = src0, hi = src1)
__device__ __forceinline__ unsigned cvtpk(float lo, float hi) {
    unsigned r;
    asm("v_cvt_pk_bf16_f32 %0, %1, %2" : "=v"(r) : "v"(lo), "v"(hi));
    return r;
}
// swap lanes[32:63] of a with lanes[0:31] of b (in place).
// ONLY safe when a and b hold provably distinct values (round-8 lesson: equal-valued
// "+v" operands can be register-coalesced into v_permlane32_swap v0,v0 -> wrong result).
#define PSWAP(a, b) asm volatile("v_permlane32_swap_b32 %0, %1" : "+v"(a), "+v"(b))

__device__ __forceinline__ f32x16 zero16() {
    f32x16 z;
#pragma unroll
    for (int j = 0; j < 16; j++) z[j] = 0.f;
    return z;
}

// B=8, C=256, H=W=64, N=4096, HID=128
#define NB 8
#define NC 256
#define NN 4096
#define HID 128
#define ELEMS (NB * NN * HID)            // 4,194,304 per [B,N,128] 16-bit buffer

// ---------------- kernel 1: projections v3 ----------------
// theta/phi: fp16 single-term MFMA. g: bf16 1-term.
// Outputs: theta -> Qf fp16 (pre-scaled by sqrt(128)*log2e), phi -> Kf fp16, g -> Vt bf16.
__global__ __launch_bounds__(256, 2)
void proj_kernel(const float* __restrict__ x,
                 const float* __restrict__ w_theta,
                 const float* __restrict__ w_phi,
                 const float* __restrict__ w_g,
                 unsigned short* __restrict__ Qf, unsigned short* __restrict__ Kf,
                 unsigned short* __restrict__ Vt) {
    __shared__ __align__(16) unsigned char LdsRaw[128 * 65 * 4];  // 33,280 B (union)
    float (*xs)[129] = reinterpret_cast<float(*)[129]>(LdsRaw);
    unsigned int (*Tb)[65] = reinterpret_cast<unsigned int(*)[65]>(LdsRaw);

    const int t = threadIdx.x;
    const int w = t >> 6, lane = t & 63;
    const int g = lane >> 4, c = lane & 15;
    const int n0 = blockIdx.x * 128;
    const int which = blockIdx.y;
    const int b = blockIdx.z;
    const float* wsel = (which == 0) ? w_theta : ((which == 1) ? w_phi : w_g);

    f32x4 acc[2][8];
#pragma unroll
    for (int mi = 0; mi < 2; mi++)
#pragma unroll
        for (int nt = 0; nt < 8; nt++) acc[mi][nt] = (f32x4){0.f, 0.f, 0.f, 0.f};

    const int srow = w * 16 + (lane >> 2);
    const int snq = (lane & 3) * 32;

    for (int k0 = 0; k0 < NC; k0 += 64) {
        __syncthreads();
        {
            const float* src = x + ((size_t)(b * NC + k0 + srow)) * NN + n0 + snq;
            float4 v[8];
#pragma unroll
            for (int u = 0; u < 8; u++) v[u] = *(const float4*)(src + 4 * u);
#pragma unroll
            for (int u = 0; u < 8; u++) {
                xs[srow][snq + 4 * u + 0] = v[u].x;
                xs[srow][snq + 4 * u + 1] = v[u].y;
                xs[srow][snq + 4 * u + 2] = v[u].z;
                xs[srow][snq + 4 * u + 3] = v[u].w;
            }
        }
        __syncthreads();

        if (which < 2) {
            // ---- fp16 single-term path (theta / phi) ----
#pragma unroll
            for (int s = 0; s < 2; s++) {
                f16x8 wf2[2];
#pragma unroll
                for (int mi = 0; mi < 2; mi++) {
                    const float* wp = wsel + (size_t)(w * 32 + mi * 16 + c) * NC + k0 + s * 32 + g * 8;
                    float av[8];
                    *(float4*)&av[0] = *(const float4*)wp;
                    *(float4*)&av[4] = *(const float4*)(wp + 4);
#pragma unroll
                    for (int j = 0; j < 8; j++) wf2[mi][j] = (_Float16)av[j];
                }
#pragma unroll
                for (int nt = 0; nt < 8; nt++) {
                    f16x8 xf;
#pragma unroll
                    for (int j = 0; j < 8; j++) xf[j] = (_Float16)xs[s * 32 + g * 8 + j][nt * 16 + c];
#pragma unroll
                    for (int mi = 0; mi < 2; mi++)
                        acc[mi][nt] = MFMA16F(wf2[mi], xf, acc[mi][nt]);
                }
            }
        } else {
            // ---- bf16 1-term path (g) ----
#pragma unroll
            for (int s = 0; s < 2; s++) {
                bf16x8 wh[2];
#pragma unroll
                for (int mi = 0; mi < 2; mi++) {
                    const float* wp = wsel + (size_t)(w * 32 + mi * 16 + c) * NC + k0 + s * 32 + g * 8;
                    float av[8];
                    *(float4*)&av[0] = *(const float4*)wp;
                    *(float4*)&av[4] = *(const float4*)(wp + 4);
#pragma unroll
                    for (int j = 0; j < 8; j++) wh[mi][j] = (short)f2bf(av[j]);
                }
#pragma unroll
                for (int nt = 0; nt < 8; nt++) {
                    bf16x8 xh;
#pragma unroll
                    for (int j = 0; j < 8; j++) xh[j] = (short)f2bf(xs[s * 32 + g * 8 + j][nt * 16 + c]);
#pragma unroll
                    for (int mi = 0; mi < 2; mi++)
                        acc[mi][nt] = MFMA16(wh[mi], xh, acc[mi][nt]);
                }
            }
        }
    }

    if (which == 2) {
#pragma unroll
        for (int mi = 0; mi < 2; mi++)
#pragma unroll
            for (int nt = 0; nt < 8; nt++)
#pragma unroll
                for (int r = 0; r < 4; r++) {
                    int o = w * 32 + mi * 16 + 4 * g + r;
                    Vt[((size_t)(b * HID + o)) * NN + n0 + nt * 16 + c] = f2bf(acc[mi][nt][r]);
                }
    } else {
        unsigned short* dh = (which == 0) ? Qf : Kf;
        const float qscale = (which == 0) ? 16.32223142f : 1.0f;  // sqrt(128)*log2(e) into theta
        for (int h = 0; h < 2; h++) {
            __syncthreads();   // protects xs->Tb union reuse
#pragma unroll
            for (int mi = 0; mi < 2; mi++)
#pragma unroll
                for (int q2 = 0; q2 < 4; q2++) {
                    int nt = h * 4 + q2;
#pragma unroll
                    for (int r = 0; r < 4; r++)
                        Tb[w * 32 + mi * 16 + 4 * g + r][q2 * 16 + c] =
                            (unsigned)f2h(acc[mi][nt][r] * qscale);
                }
            __syncthreads();
            {
                int nl = t & 63;
                int og = (t >> 6) * 32;
                int n = n0 + h * 64 + nl;
                u16x8 vh[4];
#pragma unroll
                for (int k = 0; k < 32; k++)
                    vh[k >> 3][k & 7] = (unsigned short)Tb[og + k][nl];
                size_t base = ((size_t)(b * NN + n)) * HID + og;
#pragma unroll
                for (int q = 0; q < 4; q++)
                    *(u16x8*)(dh + base + q * 8) = vh[q];
            }
        }
    }
}

// ---------------- kernel 2: flash attention v8 — fp16 single-term QK^T, 32KB LDS ----------------
// 4 waves/256 thr, wave owns 32 q-rows. KVBLK=32, double-buffered 32KB LDS (K 8K + V 8K per
// buf); 4 gll16/wave (vmcnt(4)). QK^T = 8 MFMA32F into ONE accumulator; PV = 8 MFMA32 bf16.
// 3 waves/SIMD, 3 blocks/CU. Lane-local softmax, defer-max, cvt_pk+pswap P.
template<int ZBITS>
__global__ __launch_bounds__(256, 3)
void attn_kernel(const unsigned short* __restrict__ Qf, const unsigned short* __restrict__ Kf,
                 const unsigned short* __restrict__ Vt,
                 unsigned short* __restrict__ Yp, float* __restrict__ Ms, float* __restrict__ Ss,
                 int kv_len) {
    __shared__ __align__(16) unsigned char KV_lds[2][16384];   // K [0,8K) V [8K,16K)

    const int t = threadIdx.x;
    const int w = t >> 6, lane = t & 63;
    const int l31 = lane & 31, hi = lane >> 5;
    const int bid = blockIdx.x;
    const int b = bid & 7;                                  // batch -> XCD pin
    const int z = (bid >> 3) & ((1 << ZBITS) - 1);
    const int qx = bid >> (3 + ZBITS);
    const int q0 = qx * 128 + w * 32;

    const int kvb = z * kv_len;
    const char* KG = (const char*)(Kf + ((size_t)(b * NN) + kvb) * HID);
    const char* VG = (const char*)(Vt + ((size_t)(b * HID)) * NN + kvb);

    // staging lane constants: wave w handles slots {2w, 2w+1} of K and of V
    const int si0 = w * 2, si1 = w * 2 + 1;
    const int krow0 = si0 * 4 + (lane >> 4), krow1 = si1 * 4 + (lane >> 4);  // K rows 0..31
    const int kq = lane & 15;
    const int kqg0 = kq ^ (krow0 & 15), kqg1 = kq ^ (krow1 & 15);            // 16-chunk swizzle
    const int vrow0 = si0 * 16 + (lane >> 2), vrow1 = si1 * 16 + (lane >> 2); // V rows 0..127
    const int vm = lane & 3;
    const int vmg0 = vm ^ ((vrow0 >> 1) & 3), vmg1 = vm ^ ((vrow1 >> 1) & 3);

#define STAGE(buf, kvoff)                                                                        \
    do {                                                                                         \
        gll16(KG + (size_t)((kvoff) + krow0) * 256 + kqg0 * 16, (buf) + si0 * 1024);             \
        gll16(KG + (size_t)((kvoff) + krow1) * 256 + kqg1 * 16, (buf) + si1 * 1024);             \
        gll16(VG + (size_t)vrow0 * 8192 + (size_t)(kvoff) * 2 + vmg0 * 16, (buf) + 8192 + si0 * 1024); \
        gll16(VG + (size_t)vrow1 * 8192 + (size_t)(kvoff) * 2 + vmg1 * 16, (buf) + 8192 + si1 * 1024); \
    } while (0)

    STAGE(&KV_lds[0][0], 0);   // prologue: tile 0 -> buf 0

    // Q fragments (fp16, B-operand, 32 rows): lane reads Q[q0+l31][k = 16s + hi*8 .. +7]
    f16x8 qf[8];
    {
        const unsigned short* qp = Qf + ((size_t)(b * NN) + q0 + l31) * HID + hi * 8;
#pragma unroll
        for (int s = 0; s < 8; s++) qf[s] = *(const f16x8*)(qp + s * 16);
    }

    float mstar = -3.0e38f, sacc = 0.f;   // per-lane, q = l31 (exp2-domain; Q pre-scaled)
    f32x16 yacc[4];
#pragma unroll
    for (int dt = 0; dt < 4; dt++) yacc[dt] = zero16();

    const int ntl = kv_len >> 5;   // KVBLK=32
    int cur = 0;
    const int krbase = l31 * 256;
    const int kkey = l31 & 15;
    const int vkey = (l31 >> 1) & 3;

    for (int tI = 0; tI < ntl; ++tI) {
        if (tI + 1 < ntl) {
            STAGE(&KV_lds[cur ^ 1][0], (tI + 1) * 32);
            asm volatile("s_waitcnt vmcnt(4)" ::: "memory");   // tile tI landed, tI+1 in flight
        } else {
            asm volatile("s_waitcnt vmcnt(0)" ::: "memory");
        }
        __builtin_amdgcn_sched_barrier(0);
        __builtin_amdgcn_s_barrier();

        const unsigned char* K_l = &KV_lds[cur][0];
        const unsigned char* V_l = &KV_lds[cur][8192];

        // ---- swapped QK^T: S^T = K * Q (fp16 single-term, ONE accumulator) ----
        f32x16 stv = zero16();
        __builtin_amdgcn_s_setprio(1);
#pragma unroll
        for (int s = 0; s < 8; s++) {
            const int off = krbase + (((2 * s + hi) ^ kkey) * 16);
            f16x8 kf = *(const f16x8*)(K_l + off);
            stv = MFMA32F(kf, qf[s], stv);
        }
        __builtin_amdgcn_s_setprio(0);
        // lane: q=l31; k-row = (r&3)+8*(r>>2)+4*hi per reg r; values in exp2-domain

        // ---- softmax (lane-local; one cross-half shfl max) ----
        float m = stv[0];
#pragma unroll
        for (int r = 1; r < 16; r++) m = fmaxf(m, stv[r]);
        m = fmaxf(m, __shfl_xor(m, 32));

        if (__any(m > mstar + 65.f)) {         // defer-max: rescale only on headroom breach
            float nm = fmaxf(mstar, m);
            float corr = exp2f(mstar - nm);    // first tile: ~0
            mstar = nm;
            sacc *= corr;
            float cr[16];
#pragma unroll
            for (int r = 0; r < 16; r++)
                cr[r] = __shfl(corr, (r & 3) + 8 * (r >> 2) + 4 * hi);  // corr of q-row of reg r
#pragma unroll
            for (int dt = 0; dt < 4; dt++)
#pragma unroll
                for (int r = 0; r < 16; r++) yacc[dt][r] *= cr[r];
        }

        float p[16];
#pragma unroll
        for (int r = 0; r < 16; r++) p[r] = exp2f(stv[r] - mstar);
        float ls = 0.f;
#pragma unroll
        for (int r = 0; r < 16; r++) ls += p[r];
        sacc += ls;

        // ---- P -> PV A-frag in registers: 8 cvt_pk + 4 permlane32_swap (distinct values) ----
        unsigned X0 = cvtpk(p[0], p[1]),   X1 = cvtpk(p[2], p[3]);
        unsigned X2 = cvtpk(p[4], p[5]),   X3 = cvtpk(p[6], p[7]);
        unsigned X4 = cvtpk(p[8], p[9]),   X5 = cvtpk(p[10], p[11]);
        unsigned X6 = cvtpk(p[12], p[13]), X7 = cvtpk(p[14], p[15]);
        PSWAP(X0, X2); PSWAP(X1, X3);      // k 0..15 frag
        PSWAP(X4, X6); PSWAP(X5, X7);      // k 16..31 frag
        union { unsigned u[4]; bf16x8 v; } pa, pb;
        pa.u[0] = X0; pa.u[1] = X1; pa.u[2] = X2; pa.u[3] = X3;
        pb.u[0] = X4; pb.u[1] = X5; pb.u[2] = X6; pb.u[3] = X7;
        bf16x8 pf0 = pa.v, pf1 = pb.v;

        // ---- PV: Y += P * V (bf16) ----
        __builtin_amdgcn_s_setprio(1);
#pragma unroll
        for (int dt = 0; dt < 4; dt++) {
            const int vbase = (dt * 32 + l31) * 64;
            bf16x8 v0 = *(const bf16x8*)(V_l + vbase + ((hi ^ vkey) * 16));
            bf16x8 v1 = *(const bf16x8*)(V_l + vbase + (((2 + hi) ^ vkey) * 16));
            yacc[dt] = MFMA32(pf0, v0, yacc[dt]);
            yacc[dt] = MFMA32(pf1, v1, yacc[dt]);
        }
        __builtin_amdgcn_s_setprio(0);

        __builtin_amdgcn_sched_barrier(0);
        __builtin_amdgcn_s_barrier();          // buf[cur] reads done before next overwrite
        cur ^= 1;
    }

    float stot = sacc + __shfl_xor(sacc, 32);  // total row-sum for q=l31

    if (ZBITS == 0) {
        float inv = 1.0f / stot;
        float ivr[16];
#pragma unroll
        for (int r = 0; r < 16; r++)
            ivr[r] = __shfl(inv, (r & 3) + 8 * (r >> 2) + 4 * hi);
        const size_t obase = (size_t)(b * NN) + q0;
#pragma unroll
        for (int dt = 0; dt < 4; dt++)
#pragma unroll
            for (int r = 0; r < 16; r++) {
                int q = (r & 3) + 8 * (r >> 2) + 4 * hi;
                Yp[(obase + q) * HID + dt * 32 + l31] = f2bf(yacc[dt][r] * ivr[r]);
            }
    } else {
        const size_t base = (((size_t)z * NB + b) * NN + q0);
#pragma unroll
        for (int dt = 0; dt < 4; dt++)
#pragma unroll
            for (int r = 0; r < 16; r++) {
                int q = (r & 3) + 8 * (r >> 2) + 4 * hi;
                Yp[(base + q) * HID + dt * 32 + l31] = f2bf(yacc[dt][r]);
            }
        if (hi == 0) {
            Ms[base + l31] = mstar;
            Ss[base + l31] = stot;
        }
    }
#undef STAGE
}

// ---------------- kernel 3: output projection — bf16 MFMA + residual ----------------
template<int NS>
__global__ __launch_bounds__(256, 2)
void out_kernel(const float* __restrict__ x, const float* __restrict__ w_out,
                const unsigned short* __restrict__ Yp,
                const float* __restrict__ Ms, const float* __restrict__ Ss,
                float* __restrict__ out) {
    __shared__ __align__(16) unsigned short Yl[128][136];  // 34,816 B

    const int t = threadIdx.x;
    const int w = t >> 6, lane = t & 63;
    const int g = lane >> 4, c = lane & 15;
    const int n0 = blockIdx.x * 128;
    const int b = blockIdx.y;

    {   // stage (+combine) Y tile
        int nl = t >> 1, oh = (t & 1) * 64;
        size_t qi = (size_t)b * NN + n0 + nl;
        if (NS == 0) {
            const unsigned short* src = Yp + qi * HID + oh;
#pragma unroll
            for (int i = 0; i < 8; i++)
                *(u16x8*)&Yl[nl][oh + i * 8] = *(const u16x8*)(src + i * 8);
        } else {
            const size_t NBNN = (size_t)NB * NN;
            float Mv[NS > 0 ? NS : 1], Wt[NS > 0 ? NS : 1];
            float M = -3.0e38f;
#pragma unroll
            for (int zz = 0; zz < NS; zz++) { Mv[zz] = Ms[zz * NBNN + qi]; M = fmaxf(M, Mv[zz]); }
            float S = 0.f;
#pragma unroll
            for (int zz = 0; zz < NS; zz++) { Wt[zz] = exp2f(Mv[zz] - M); S += Ss[zz * NBNN + qi] * Wt[zz]; }
            float invS = 1.f / S;
#pragma unroll
            for (int zz = 0; zz < NS; zz++) Wt[zz] *= invS;
#pragma unroll
            for (int i = 0; i < 8; i++) {
                float f[8] = {0.f, 0.f, 0.f, 0.f, 0.f, 0.f, 0.f, 0.f};
#pragma unroll
                for (int zz = 0; zz < NS; zz++) {
                    u16x8 a = *(const u16x8*)(Yp + (zz * NBNN + qi) * HID + oh + i * 8);
#pragma unroll
                    for (int j = 0; j < 8; j++) f[j] = fmaf(bf2f(a[j]), Wt[zz], f[j]);
                }
                u16x8 vv;
#pragma unroll
                for (int j = 0; j < 8; j++) vv[j] = f2bf(f[j]);
                *(u16x8*)&Yl[nl][oh + i * 8] = vv;
            }
        }
    }
    __syncthreads();

    f32x4 acc[4][8];
#pragma unroll
    for (int mi = 0; mi < 4; mi++)
#pragma unroll
        for (int nt = 0; nt < 8; nt++) acc[mi][nt] = (f32x4){0.f, 0.f, 0.f, 0.f};

#pragma unroll
    for (int s = 0; s < 4; s++) {
        bf16x8 wf[4];
#pragma unroll
        for (int mi = 0; mi < 4; mi++) {
            const float* wp = w_out + (size_t)(w * 64 + mi * 16 + c) * HID + s * 32 + g * 8;
            float av[8];
            *(float4*)&av[0] = *(const float4*)wp;
            *(float4*)&av[4] = *(const float4*)(wp + 4);
#pragma unroll
            for (int j = 0; j < 8; j++) wf[mi][j] = (short)f2bf(av[j]);
        }
#pragma unroll
        for (int nt = 0; nt < 8; nt++) {
            bf16x8 yf = *(const bf16x8*)&Yl[nt * 16 + c][s * 32 + g * 8];
#pragma unroll
            for (int mi = 0; mi < 4; mi++) acc[mi][nt] = MFMA16(wf[mi], yf, acc[mi][nt]);
        }
    }

#pragma unroll
    for (int mi = 0; mi < 4; mi++)
#pragma unroll
        for (int nt = 0; nt < 8; nt++)
#pragma unroll
            for (int r = 0; r < 4; r++) {
                int cg = w * 64 + mi * 16 + 4 * g + r;
                size_t idx = ((size_t)(b * NC + cg)) * NN + n0 + nt * 16 + c;
                out[idx] = x[idx] + acc[mi][nt][r];
            }
}

// ---------------- launch ----------------
extern "C" void kernel_launch(void* const* d_in, const int* in_sizes, int n_in,
                              void* d_out, int out_size, void* d_ws, size_t ws_size,
                              hipStream_t stream) {
    const float* x = (const float*)d_in[0];
    const float* w_phi = (const float*)d_in[1];
    const float* w_theta = (const float*)d_in[2];
    const float* w_g = (const float*)d_in[3];
    const float* w_out = (const float*)d_in[4];
    float* out = (float*)d_out;

    const size_t BUF = (size_t)ELEMS * 2;      // 8,388,608 B per 16-bit buffer
    const size_t MSB = (size_t)NB * NN * 4;    // 131,072 B per [B,N] f32 array
    if (ws_size < 4 * BUF) return;

    unsigned short* Qf = (unsigned short*)d_ws;
    unsigned short* Kf = (unsigned short*)((char*)d_ws + 1 * BUF);
    unsigned short* Vt = (unsigned short*)((char*)d_ws + 2 * BUF);

    proj_kernel<<<dim3(32, 3, 8), 256, 0, stream>>>(x, w_theta, w_phi, w_g, Qf, Kf, Vt);

    if (ws_size >= 7 * BUF + 8 * MSB) {
        // split-kv x4: 1024 blocks x 256 thr (8b x 4z x 32qx), 3 blocks/CU resident
        unsigned short* Yp = (unsigned short*)((char*)d_ws + 3 * BUF);
        float* Ms = (float*)((char*)d_ws + 7 * BUF);
        float* Ss = (float*)((char*)d_ws + 7 * BUF + 4 * MSB);
        attn_kernel<2><<<dim3(1024), 256, 0, stream>>>(Qf, Kf, Vt, Yp, Ms, Ss, NN / 4);
        out_kernel<4><<<dim3(32, NB), 256, 0, stream>>>(x, w_out, Yp, Ms, Ss, out);
    } else if (ws_size >= 5 * BUF + 4 * MSB) {
        // split-kv x2 fallback: 512 blocks x 256 thr
        unsigned short* Yp = (unsigned short*)((char*)d_ws + 3 * BUF);
        float* Ms = (float*)((char*)d_ws + 5 * BUF);
        float* Ss = (float*)((char*)d_ws + 5 * BUF + 2 * MSB);
        attn_kernel<1><<<dim3(512), 256, 0, stream>>>(Qf, Kf, Vt, Yp, Ms, Ss, NN / 2);
        out_kernel<2><<<dim3(32, NB), 256, 0, stream>>>(x, w_out, Yp, Ms, Ss, out);
    } else {
        unsigned short* Yb = (unsigned short*)((char*)d_ws + 3 * BUF);
        attn_kernel<0><<<dim3(256), 256, 0, stream>>>(Qf, Kf, Vt, Yb, nullptr, nullptr, NN);
        out_kernel<0><<<dim3(32, NB), 256, 0, stream>>>(x, w_out, Yb, nullptr, nullptr, out);
    }
}